// Round 21
// baseline (654.284 us; speedup 1.0000x reference)
//
#include <hip/hip_runtime.h>
#include <math.h>

#define T_ 4096
#define D_ 128
#define R_ 8

// LDS-only barrier: drains lgkmcnt, leaves global prefetches (vmcnt) in flight.
#define LDS_BARRIER() asm volatile("s_waitcnt lgkmcnt(0)\n\ts_barrier" ::: "memory")

typedef float f32x4 __attribute__((ext_vector_type(4)));
typedef float f32x16 __attribute__((ext_vector_type(16)));
typedef _Float16 f16x8 __attribute__((ext_vector_type(8)));
typedef unsigned short u16x8 __attribute__((ext_vector_type(8)));

__device__ __forceinline__ unsigned short f2h_bits(float f) {
    _Float16 h = (_Float16)f;
    return __builtin_bit_cast(unsigned short, h);
}

__device__ __forceinline__ unsigned long long pack4h(float a, float b, float c, float d) {
    unsigned int lo = __builtin_bit_cast(unsigned int, __builtin_amdgcn_cvt_pkrtz(a, b));
    unsigned int hi = __builtin_bit_cast(unsigned int, __builtin_amdgcn_cvt_pkrtz(c, d));
    return ((unsigned long long)hi << 32) | (unsigned long long)lo;
}

// tanh(x) = 1 - 2/(exp2(2*log2e*x)+1); large-|x| safe
__device__ __forceinline__ float tanh_fast(float x) {
    float e = __builtin_amdgcn_exp2f(x * 2.885390082f);
    float r = __builtin_amdgcn_rcpf(e + 1.0f);
    return fmaf(-2.0f, r, 1.0f);
}

// tanh-approx GELU: |err| ~1e-3 vs erf form (budget is 2%)
__device__ __forceinline__ float gelu_fast(float x) {
    float x2 = x * x;
    float u = x * fmaf(x2, 0.044715f, 1.0f);
    float e = __builtin_amdgcn_exp2f(u * -2.3022082f);
    return x * __builtin_amdgcn_rcpf(1.0f + e);
}

__device__ __forceinline__ float gelu_exact(float x) {
    return 0.5f * x * (1.0f + erff(x * 0.7071067811865475f));
}

// ---------------------------------------------------------------------------
// Selector MLPs (tiny): hdr[0]=n_evolve, hdr[1]=alpha, hdr[2..9]=rule_weights
// ---------------------------------------------------------------------------
__global__ void selectors_kernel(
    const float* __restrict__ c,
    const float* __restrict__ rW1, const float* __restrict__ rb1,
    const float* __restrict__ rW2, const float* __restrict__ rb2,
    const float* __restrict__ sW1, const float* __restrict__ sb1,
    const float* __restrict__ sW2, const float* __restrict__ sb2,
    const float* __restrict__ aW1, const float* __restrict__ ab1,
    const float* __restrict__ aW2, const float* __restrict__ ab2,
    float* __restrict__ hdr)
{
    __shared__ float cs[128];
    __shared__ float hb[64];
    __shared__ float lg[8];
    const int l = threadIdx.x;  // 64 threads
    cs[l] = c[l];
    cs[l + 64] = c[l + 64];
    __syncthreads();

    // rule selector: 128 -> 64 -> 8 -> softmax
    {
        float acc = rb1[l];
        for (int k = 0; k < 128; ++k) acc += cs[k] * rW1[k * 64 + l];
        hb[l] = gelu_exact(acc);
    }
    __syncthreads();
    if (l < 8) {
        float acc = rb2[l];
        for (int j = 0; j < 64; ++j) acc += hb[j] * rW2[j * 8 + l];
        lg[l] = acc;
    }
    __syncthreads();
    if (l == 0) {
        float mx = lg[0];
        for (int o = 1; o < 8; ++o) mx = fmaxf(mx, lg[o]);
        float e[8], se = 0.0f;
        for (int o = 0; o < 8; ++o) { e[o] = expf(lg[o] - mx); se += e[o]; }
        for (int o = 0; o < 8; ++o) hdr[2 + o] = e[o] / se;
    }
    __syncthreads();

    // steps selector: 128 -> 32 -> 7 -> softmax -> n_evolve
    if (l < 32) {
        float acc = sb1[l];
        for (int k = 0; k < 128; ++k) acc += cs[k] * sW1[k * 32 + l];
        hb[l] = gelu_exact(acc);
    }
    __syncthreads();
    if (l < 7) {
        float acc = sb2[l];
        for (int j = 0; j < 32; ++j) acc += hb[j] * sW2[j * 7 + l];
        lg[l] = acc;
    }
    __syncthreads();
    if (l == 0) {
        float mx = lg[0];
        for (int o = 1; o < 7; ++o) mx = fmaxf(mx, lg[o]);
        float e[7], se = 0.0f;
        for (int o = 0; o < 7; ++o) { e[o] = expf(lg[o] - mx); se += e[o]; }
        float n_soft = 0.0f;
        for (int o = 0; o < 7; ++o) n_soft += (e[o] / se) * (float)(2 + o);
        int ne = (int)floorf(n_soft + 0.5f);
        ne = ne < 2 ? 2 : (ne > 8 ? 8 : ne);
        hdr[0] = (float)ne;
    }
    __syncthreads();

    // alpha selector: 128 -> 32 -> 1 -> sigmoid
    if (l < 32) {
        float acc = ab1[l];
        for (int k = 0; k < 128; ++k) acc += cs[k] * aW1[k * 32 + l];
        hb[l] = gelu_exact(acc);
    }
    __syncthreads();
    if (l == 0) {
        float acc = ab2[0];
        for (int j = 0; j < 32; ++j) acc += hb[j] * aW2[j];
        hdr[1] = 0.1f + 0.8f / (1.0f + expf(-acc));
    }
}

// ---------------------------------------------------------------------------
// Weight prep -> FRAGMENT-ORDERED layout for 32x32x16 MFMA.
// W1F block (r, ks16 in 0..23, nb in 0..7): 64 lanes x 16B; lane holds
//   n = nb*32 + (lane&31), k = ks16*16 + (lane>>5)*8 .. +8.
// W2F block (r, ks in 0..15, nb2 in 0..3): same pattern over 128 n / 256 k.
// A wave fragment load = one contiguous 1KB access (coalesced, R17 win).
// ---------------------------------------------------------------------------
__global__ __launch_bounds__(256) void prep_weights(
    const float* __restrict__ W1, const float* __restrict__ W2,
    unsigned short* __restrict__ W1F, unsigned short* __restrict__ W2F)
{
    const int bx = blockIdx.x;
    const int t = threadIdx.x;
    if (bx < 192) {                     // W1: (r, ks16) pairs, 8*24
        const int r = bx / 24;
        const int ks = bx % 24;
#pragma unroll
        for (int i = 0; i < 2; ++i) {
            const int idx = i * 256 + t;                  // 0..511 = nb*64+lane
            const int nb = idx >> 6;
            const int lane = idx & 63;
            const int n = nb * 32 + (lane & 31);
            const int k0 = ks * 16 + (lane >> 5) * 8;
            u16x8 v;
#pragma unroll
            for (int j = 0; j < 8; ++j)
                v[j] = f2h_bits(W1[((size_t)r * 384 + k0 + j) * 256 + n]);
            *reinterpret_cast<u16x8*>(W1F + ((size_t)bx * 8 + nb) * 512 + lane * 8) = v;
        }
    } else {                            // W2: (r, ks) pairs, 8*16
        const int b2 = bx - 192;
        const int r = b2 / 16;
        const int ks = b2 % 16;
        const int nb = t >> 6;          // 0..3
        const int lane = t & 63;
        const int n = nb * 32 + (lane & 31);
        const int k0 = ks * 16 + (lane >> 5) * 8;
        u16x8 v;
#pragma unroll
        for (int j = 0; j < 8; ++j)
            v[j] = f2h_bits(W2[((size_t)r * 256 + k0 + j) * 128 + n]);
        *reinterpret_cast<u16x8*>(W2F + ((size_t)b2 * 4 + nb) * 512 + lane * 8) = v;
    }
}

// ---------------------------------------------------------------------------
// One evolution step, 32x32x16 MFMA. 4 waves (256 thr), tile 64 rows,
// grid 512 (2 blocks/CU), single Hs, LDS-only barriers, launch_bounds(256,2).
// Half the MFMA instruction count of the 16x16x32 version at a ~15% higher
// pipe rate (2382 vs 2075 TF ceiling); LDS traffic unchanged.
// A/B k-mapping: k = (lane>>5)*8+e on BOTH operands (consistent bijection).
// C/D (m74/m101): col(t) = lane&31, row(n) = (reg&3)+8*(reg>>2)+4*(lane>>5).
// ---------------------------------------------------------------------------
__global__ __launch_bounds__(256, 2) void evolve_step(
    int step,
    const float* __restrict__ cells_in,
    float* __restrict__ buf0,
    float* __restrict__ buf1,
    const unsigned short* __restrict__ W1F,
    const unsigned short* __restrict__ W2F,
    const float* __restrict__ b1,
    const float* __restrict__ b2,
    const float* __restrict__ hdr)
{
    if (step >= (int)hdr[0]) return;
    const float* src = (step == 0) ? cells_in : ((step & 1) ? buf0 : buf1);
    float* dst = (step & 1) ? buf1 : buf0;
    const float alpha = hdr[1];

    __shared__ __align__(16) unsigned short Xs[66 * 128];   // 16.9 KB
    __shared__ __align__(16) unsigned short Hs[64 * 256];   // 32 KB

    const int tid = threadIdx.x;
    const int blk = blockIdx.x;
    const int b = blk >> 6;
    const int t0 = (blk & 63) << 6;
    const float* srcb = src + (size_t)b * (T_ * D_);

    // ---- stage X tile (float4 load -> pack4h -> b64 swizzled store) ----
    {
        const int cr = (tid & 31) << 2;
        for (int j = (tid >> 5); j < 66; j += 8) {
            const int tg = (t0 + j - 1) & (T_ - 1);
            const f32x4 v = *reinterpret_cast<const f32x4*>(srcb + tg * D_ + cr);
            int byte = (j * 128 + cr) * 2;
            byte ^= (j & 7) << 4;
            *reinterpret_cast<unsigned long long*>(reinterpret_cast<char*>(Xs) + byte) =
                pack4h(v[0], v[1], v[2], v[3]);
        }
    }
    __syncthreads();

    const int wave = tid >> 6;           // 0..3
    const int lane = tid & 63;
    const int l32 = lane & 31;
    const int lk = lane >> 5;            // 0/1 : k-subgroup
    const char* Xsb = reinterpret_cast<const char*>(Xs);
    char* Hsb = reinterpret_cast<char*>(Hs);

    f32x16 facc[2];   // [tb] -- wave owns 32 O-cols x 64 rows
#pragma unroll
    for (int tb = 0; tb < 2; ++tb)
#pragma unroll
        for (int i = 0; i < 16; ++i) facc[tb][i] = 0.0f;

    const int lane8 = lane * 8;

#pragma unroll 1
    for (int r = 0; r < R_; ++r) {
        // W1F wave base: block (r, ks, nb=wave*2+{0,1})
        const unsigned short* w1r = W1F + ((size_t)r * 24 * 8 + wave * 2) * 512 + lane8;
        // W2F wave base: block (r, ks, nb2=wave)
        const unsigned short* w2r = W2F + ((size_t)r * 16 * 4 + wave) * 512 + lane8;

        // ======== rule-top: long-cover loads ========
        f16x8 w1f[3][2];     // GEMM1 weight slots (depth-2 rotation), ks stride 8*512
        f16x8 wfr2[3];       // GEMM2 weight slots, ks stride 4*512
        f16x8 xfr[2][2];     // X fragments, dbuf x 2 t-blocks
        f16x8 hfr[2][2];     // H fragments, dbuf x 2 t-blocks
        f32x4 bv1[2][4], bv2[4];

        w1f[0][0] = __builtin_bit_cast(f16x8, *reinterpret_cast<const u16x8*>(w1r));
        w1f[0][1] = __builtin_bit_cast(f16x8, *reinterpret_cast<const u16x8*>(w1r + 512));
        w1f[1][0] = __builtin_bit_cast(f16x8, *reinterpret_cast<const u16x8*>(w1r + 4096));
        w1f[1][1] = __builtin_bit_cast(f16x8, *reinterpret_cast<const u16x8*>(w1r + 4096 + 512));
        wfr2[0]   = __builtin_bit_cast(f16x8, *reinterpret_cast<const u16x8*>(w2r));
        wfr2[1]   = __builtin_bit_cast(f16x8, *reinterpret_cast<const u16x8*>(w2r + 2048));
#pragma unroll
        for (int nb = 0; nb < 2; ++nb)
#pragma unroll
            for (int q = 0; q < 4; ++q)
                bv1[nb][q] = *reinterpret_cast<const f32x4*>(
                    b1 + r * 256 + wave * 64 + nb * 32 + q * 8 + lk * 4);
#pragma unroll
        for (int q = 0; q < 4; ++q)
            bv2[q] = *reinterpret_cast<const f32x4*>(
                b2 + r * 128 + wave * 32 + q * 8 + lk * 4);
#pragma unroll
        for (int tb = 0; tb < 2; ++tb) {
            const int row = tb * 32 + l32 + 1;   // ks=0: seg 0 -> rowadd 1
            int byte = row * 256 + lk * 16;
            byte ^= (row & 7) << 4;
            xfr[0][tb] = __builtin_bit_cast(f16x8,
                *reinterpret_cast<const u16x8*>(Xsb + byte));
        }

        // ============ GEMM1: H^T = W1^T X^T (24 k-steps of 16) ============
        f32x16 acc1[2][2];   // [nb][tb]
#pragma unroll
        for (int nb = 0; nb < 2; ++nb)
#pragma unroll
            for (int tb = 0; tb < 2; ++tb)
#pragma unroll
                for (int i = 0; i < 16; ++i) acc1[nb][tb][i] = 0.0f;

#pragma unroll
        for (int ks = 0; ks < 24; ++ks) {
            if (ks < 22) {
                const size_t off = (size_t)(ks + 2) * 4096;
                w1f[(ks + 2) % 3][0] = __builtin_bit_cast(f16x8,
                    *reinterpret_cast<const u16x8*>(w1r + off));
                w1f[(ks + 2) % 3][1] = __builtin_bit_cast(f16x8,
                    *reinterpret_cast<const u16x8*>(w1r + off + 512));
            }
            if (ks < 23) {
                const int kn = ks + 1;
                const int seg = kn >> 3;
                const int rowadd = (seg == 0) ? 1 : ((seg == 1) ? 0 : 2);
                const int kloc = (kn & 7) * 32 + lk * 16;
#pragma unroll
                for (int tb = 0; tb < 2; ++tb) {
                    const int row = tb * 32 + l32 + rowadd;
                    int byte = row * 256 + kloc;
                    byte ^= (row & 7) << 4;
                    xfr[(ks + 1) & 1][tb] = __builtin_bit_cast(f16x8,
                        *reinterpret_cast<const u16x8*>(Xsb + byte));
                }
            }
            __builtin_amdgcn_s_setprio(1);
#pragma unroll
            for (int nb = 0; nb < 2; ++nb)
#pragma unroll
                for (int tb = 0; tb < 2; ++tb)
                    acc1[nb][tb] = __builtin_amdgcn_mfma_f32_32x32x16_f16(
                        w1f[ks % 3][nb], xfr[ks & 1][tb], acc1[nb][tb], 0, 0, 0);
            __builtin_amdgcn_s_setprio(0);
        }

        LDS_BARRIER();   // previous rule's GEMM2 reads of Hs complete (WAR)

        // ---- bias + GELU -> Hs (b64 swizzled writes) ----
        // lane holds t = tb*32+l32; n = wave*64 + nb*32 + q*8 + lk*4 + i
#pragma unroll
        for (int tb = 0; tb < 2; ++tb) {
            const int t = tb * 32 + l32;
            const int rowbyte = t * 512;
            const int swz = (t & 7) << 4;
#pragma unroll
            for (int nb = 0; nb < 2; ++nb) {
#pragma unroll
                for (int q = 0; q < 4; ++q) {
                    const float g0 = gelu_fast(acc1[nb][tb][q * 4 + 0] + bv1[nb][q][0]);
                    const float g1 = gelu_fast(acc1[nb][tb][q * 4 + 1] + bv1[nb][q][1]);
                    const float g2 = gelu_fast(acc1[nb][tb][q * 4 + 2] + bv1[nb][q][2]);
                    const float g3 = gelu_fast(acc1[nb][tb][q * 4 + 3] + bv1[nb][q][3]);
                    int byte = rowbyte + (wave * 64 + nb * 32 + q * 8 + lk * 4) * 2;
                    byte ^= swz;
                    *reinterpret_cast<unsigned long long*>(Hsb + byte) =
                        pack4h(g0, g1, g2, g3);
                }
            }
        }
        LDS_BARRIER();   // Hs visible to all waves (RAW)

        // ============ GEMM2: O^T = W2^T H^T (16 k-steps of 16) ============
        f32x16 acc2[2];   // [tb]
#pragma unroll
        for (int tb = 0; tb < 2; ++tb)
#pragma unroll
            for (int i = 0; i < 16; ++i) acc2[tb][i] = 0.0f;

#pragma unroll
        for (int tb = 0; tb < 2; ++tb) {
            const int t = tb * 32 + l32;
            int byte = t * 512 + lk * 16;
            byte ^= (t & 7) << 4;
            hfr[0][tb] = __builtin_bit_cast(f16x8,
                *reinterpret_cast<const u16x8*>(Hsb + byte));
        }

#pragma unroll
        for (int ks = 0; ks < 16; ++ks) {
            if (ks < 14) {
                wfr2[(ks + 2) % 3] = __builtin_bit_cast(f16x8,
                    *reinterpret_cast<const u16x8*>(w2r + (size_t)(ks + 2) * 2048));
            }
            if (ks < 15) {
                const int kloc = (ks + 1) * 32 + lk * 16;
#pragma unroll
                for (int tb = 0; tb < 2; ++tb) {
                    const int t = tb * 32 + l32;
                    int byte = t * 512 + kloc;
                    byte ^= (t & 7) << 4;
                    hfr[(ks + 1) & 1][tb] = __builtin_bit_cast(f16x8,
                        *reinterpret_cast<const u16x8*>(Hsb + byte));
                }
            }
            __builtin_amdgcn_s_setprio(1);
#pragma unroll
            for (int tb = 0; tb < 2; ++tb)
                acc2[tb] = __builtin_amdgcn_mfma_f32_32x32x16_f16(
                    wfr2[ks % 3], hfr[ks & 1][tb], acc2[tb], 0, 0, 0);
            __builtin_amdgcn_s_setprio(0);
        }

        const float rw = hdr[2 + r];
#pragma unroll
        for (int tb = 0; tb < 2; ++tb)
#pragma unroll
            for (int q = 0; q < 4; ++q)
#pragma unroll
                for (int i = 0; i < 4; ++i)
                    facc[tb][q * 4 + i] += rw * tanh_fast(acc2[tb][q * 4 + i] + bv2[q][i]);
    }

    // ---- epilogue: cells = alpha*x + (1-alpha)*new, f32x4 in/out ----
    // lane holds t = t0 + tb*32 + l32; n = wave*32 + q*8 + lk*4 + i
    float* dstb = dst + (size_t)b * (T_ * D_);
    const float om = 1.0f - alpha;
#pragma unroll
    for (int tb = 0; tb < 2; ++tb) {
        const int t = t0 + tb * 32 + l32;
#pragma unroll
        for (int q = 0; q < 4; ++q) {
            const int n0 = wave * 32 + q * 8 + lk * 4;
            const size_t idx = (size_t)t * D_ + n0;
            const f32x4 x = *reinterpret_cast<const f32x4*>(srcb + idx);
            f32x4 o;
#pragma unroll
            for (int i = 0; i < 4; ++i)
                o[i] = alpha * x[i] + om * facc[tb][q * 4 + i];
            *reinterpret_cast<f32x4*>(dstb + idx) = o;
        }
    }
}

// ---------------------------------------------------------------------------
// LayerNorm over D=128. One wave per row, 2 elems/lane.
// ---------------------------------------------------------------------------
__global__ __launch_bounds__(256) void ln_kernel(
    const float* __restrict__ buf0, const float* __restrict__ buf1,
    const float* __restrict__ hdr,
    const float* __restrict__ g, const float* __restrict__ bb,
    float* __restrict__ out)
{
    const int ne = (int)hdr[0];
    const float* src = ((ne - 1) & 1) ? buf1 : buf0;   // step s writes buf[s&1]
    const int row = blockIdx.x * 4 + (threadIdx.x >> 6);
    const int lane = threadIdx.x & 63;
    const size_t base = (size_t)row * D_;
    const int d = lane * 2;
    const float a = src[base + d];
    const float c = src[base + d + 1];
    float s = a + c;
    float q = a * a + c * c;
#pragma unroll
    for (int off = 32; off >= 1; off >>= 1) {
        s += __shfl_xor(s, off);
        q += __shfl_xor(q, off);
    }
    const float mean = s * (1.0f / 128.0f);
    float var = q * (1.0f / 128.0f) - mean * mean;
    var = fmaxf(var, 0.0f);
    const float rstd = rsqrtf(var + 1e-5f);
    out[base + d]     = (a - mean) * rstd * g[d] + bb[d];
    out[base + d + 1] = (c - mean) * rstd * g[d + 1] + bb[d + 1];
}

// ---------------------------------------------------------------------------
extern "C" void kernel_launch(void* const* d_in, const int* in_sizes, int n_in,
                              void* d_out, int out_size, void* d_ws, size_t ws_size,
                              hipStream_t stream)
{
    (void)in_sizes; (void)n_in; (void)out_size; (void)ws_size;
    const float* cells  = (const float*)d_in[0];
    const float* cst    = (const float*)d_in[1];
    const float* W1     = (const float*)d_in[2];
    const float* b1     = (const float*)d_in[3];
    const float* W2     = (const float*)d_in[4];
    const float* b2     = (const float*)d_in[5];
    const float* rW1    = (const float*)d_in[6];
    const float* rb1    = (const float*)d_in[7];
    const float* rW2    = (const float*)d_in[8];
    const float* rb2    = (const float*)d_in[9];
    const float* sW1    = (const float*)d_in[10];
    const float* sb1    = (const float*)d_in[11];
    const float* sW2    = (const float*)d_in[12];
    const float* sb2    = (const float*)d_in[13];
    const float* aW1    = (const float*)d_in[14];
    const float* ab1    = (const float*)d_in[15];
    const float* aW2    = (const float*)d_in[16];
    const float* ab2    = (const float*)d_in[17];
    const float* ln_g   = (const float*)d_in[18];
    const float* ln_b   = (const float*)d_in[19];
    float* out = (float*)d_out;

    char* ws = (char*)d_ws;
    float* hdr  = (float*)ws;                                      // 256 B
    float* buf0 = (float*)(ws + 256);                              // 16 MiB
    unsigned short* W1F = (unsigned short*)(ws + 256 + 16777216);  // 1.5 MiB
    unsigned short* W2F = W1F + (size_t)192 * 4096;                // 0.5 MiB
    float* buf1 = out;  // d_out doubles as ping-pong buffer (LN is in-place safe)

    hipLaunchKernelGGL(prep_weights, dim3(320), dim3(256), 0, stream, W1, W2, W1F, W2F);
    hipLaunchKernelGGL(selectors_kernel, dim3(1), dim3(64), 0, stream,
                       cst, rW1, rb1, rW2, rb2, sW1, sb1, sW2, sb2,
                       aW1, ab1, aW2, ab2, hdr);
    for (int s = 0; s < 8; ++s) {
        hipLaunchKernelGGL(evolve_step, dim3(512), dim3(256), 0, stream,
                           s, cells, buf0, buf1, W1F, W2F, b1, b2, hdr);
    }
    hipLaunchKernelGGL(ln_kernel, dim3(8192), dim3(256), 0, stream,
                       buf0, buf1, hdr, ln_g, ln_b, out);
}

// Round 22
// 577.931 us; speedup vs baseline: 1.1321x; 1.1321x over previous
//
#include <hip/hip_runtime.h>
#include <math.h>

#define T_ 4096
#define D_ 128
#define R_ 8

// LDS-only barrier: drains lgkmcnt, leaves global prefetches (vmcnt) in flight.
#define LDS_BARRIER() asm volatile("s_waitcnt lgkmcnt(0)\n\ts_barrier" ::: "memory")

typedef float f32x4 __attribute__((ext_vector_type(4)));
typedef _Float16 f16x8 __attribute__((ext_vector_type(8)));
typedef unsigned short u16x8 __attribute__((ext_vector_type(8)));

__device__ __forceinline__ unsigned short f2h_bits(float f) {
    _Float16 h = (_Float16)f;
    return __builtin_bit_cast(unsigned short, h);
}

__device__ __forceinline__ unsigned long long pack4h(float a, float b, float c, float d) {
    unsigned int lo = __builtin_bit_cast(unsigned int, __builtin_amdgcn_cvt_pkrtz(a, b));
    unsigned int hi = __builtin_bit_cast(unsigned int, __builtin_amdgcn_cvt_pkrtz(c, d));
    return ((unsigned long long)hi << 32) | (unsigned long long)lo;
}

// tanh(x) = 1 - 2/(exp2(2*log2e*x)+1); large-|x| safe
__device__ __forceinline__ float tanh_fast(float x) {
    float e = __builtin_amdgcn_exp2f(x * 2.885390082f);
    float r = __builtin_amdgcn_rcpf(e + 1.0f);
    return fmaf(-2.0f, r, 1.0f);
}

// tanh-approx GELU: |err| ~1e-3 vs erf form (budget is 2%)
__device__ __forceinline__ float gelu_fast(float x) {
    float x2 = x * x;
    float u = x * fmaf(x2, 0.044715f, 1.0f);
    float e = __builtin_amdgcn_exp2f(u * -2.3022082f);
    return x * __builtin_amdgcn_rcpf(1.0f + e);
}

__device__ __forceinline__ float gelu_exact(float x) {
    return 0.5f * x * (1.0f + erff(x * 0.7071067811865475f));
}

// ---------------------------------------------------------------------------
// Selector MLPs (tiny): hdr[0]=n_evolve, hdr[1]=alpha, hdr[2..9]=rule_weights
// ---------------------------------------------------------------------------
__global__ void selectors_kernel(
    const float* __restrict__ c,
    const float* __restrict__ rW1, const float* __restrict__ rb1,
    const float* __restrict__ rW2, const float* __restrict__ rb2,
    const float* __restrict__ sW1, const float* __restrict__ sb1,
    const float* __restrict__ sW2, const float* __restrict__ sb2,
    const float* __restrict__ aW1, const float* __restrict__ ab1,
    const float* __restrict__ aW2, const float* __restrict__ ab2,
    float* __restrict__ hdr)
{
    __shared__ float cs[128];
    __shared__ float hb[64];
    __shared__ float lg[8];
    const int l = threadIdx.x;  // 64 threads
    cs[l] = c[l];
    cs[l + 64] = c[l + 64];
    __syncthreads();

    // rule selector: 128 -> 64 -> 8 -> softmax
    {
        float acc = rb1[l];
        for (int k = 0; k < 128; ++k) acc += cs[k] * rW1[k * 64 + l];
        hb[l] = gelu_exact(acc);
    }
    __syncthreads();
    if (l < 8) {
        float acc = rb2[l];
        for (int j = 0; j < 64; ++j) acc += hb[j] * rW2[j * 8 + l];
        lg[l] = acc;
    }
    __syncthreads();
    if (l == 0) {
        float mx = lg[0];
        for (int o = 1; o < 8; ++o) mx = fmaxf(mx, lg[o]);
        float e[8], se = 0.0f;
        for (int o = 0; o < 8; ++o) { e[o] = expf(lg[o] - mx); se += e[o]; }
        for (int o = 0; o < 8; ++o) hdr[2 + o] = e[o] / se;
    }
    __syncthreads();

    // steps selector: 128 -> 32 -> 7 -> softmax -> n_evolve
    if (l < 32) {
        float acc = sb1[l];
        for (int k = 0; k < 128; ++k) acc += cs[k] * sW1[k * 32 + l];
        hb[l] = gelu_exact(acc);
    }
    __syncthreads();
    if (l < 7) {
        float acc = sb2[l];
        for (int j = 0; j < 32; ++j) acc += hb[j] * sW2[j * 7 + l];
        lg[l] = acc;
    }
    __syncthreads();
    if (l == 0) {
        float mx = lg[0];
        for (int o = 1; o < 7; ++o) mx = fmaxf(mx, lg[o]);
        float e[7], se = 0.0f;
        for (int o = 0; o < 7; ++o) { e[o] = expf(lg[o] - mx); se += e[o]; }
        float n_soft = 0.0f;
        for (int o = 0; o < 7; ++o) n_soft += (e[o] / se) * (float)(2 + o);
        int ne = (int)floorf(n_soft + 0.5f);
        ne = ne < 2 ? 2 : (ne > 8 ? 8 : ne);
        hdr[0] = (float)ne;
    }
    __syncthreads();

    // alpha selector: 128 -> 32 -> 1 -> sigmoid
    if (l < 32) {
        float acc = ab1[l];
        for (int k = 0; k < 128; ++k) acc += cs[k] * aW1[k * 32 + l];
        hb[l] = gelu_exact(acc);
    }
    __syncthreads();
    if (l == 0) {
        float acc = ab2[0];
        for (int j = 0; j < 32; ++j) acc += hb[j] * aW2[j];
        hdr[1] = 0.1f + 0.8f / (1.0f + expf(-acc));
    }
}

// ---------------------------------------------------------------------------
// Weight prep -> FRAGMENT-ORDERED layout (the R17 win).
// W1F block (r,kk,nb): 64 lanes x 16B, lane = lhi*16+l16 holds
//   n = nb*16+l16, k = kk*32+lhi*8 .. +8. A wave's fragment load is ONE
//   contiguous 1KB access (4 cache lines) instead of 16 scattered lines.
// ---------------------------------------------------------------------------
__global__ __launch_bounds__(256) void prep_weights(
    const float* __restrict__ W1, const float* __restrict__ W2,
    unsigned short* __restrict__ W1F, unsigned short* __restrict__ W2F)
{
    const int bx = blockIdx.x;
    const int t = threadIdx.x;
    if (bx < 96) {                      // W1: (r, kk) pairs, 8*12
        const int r = bx / 12;
        const int kk = bx % 12;
        unsigned short* dst = W1F + (size_t)bx * 8192;   // 16 nb * 64 lanes * 8
#pragma unroll
        for (int i = 0; i < 4; ++i) {
            const int idx = i * 256 + t;                  // 0..1023
            const int nb = idx >> 6;
            const int lane = idx & 63;
            const int n = nb * 16 + (lane & 15);
            const int k0 = kk * 32 + (lane >> 4) * 8;
            u16x8 v;
#pragma unroll
            for (int j = 0; j < 8; ++j)
                v[j] = f2h_bits(W1[((size_t)r * 384 + k0 + j) * 256 + n]);
            *reinterpret_cast<u16x8*>(dst + idx * 8) = v;
        }
    } else {                            // W2: (r, k2) pairs, 8*8
        const int b2 = bx - 96;
        const int r = b2 >> 3;
        const int k2 = b2 & 7;
        unsigned short* dst = W2F + (size_t)b2 * 4096;   // 8 nb * 64 * 8
#pragma unroll
        for (int i = 0; i < 2; ++i) {
            const int idx = i * 256 + t;                  // 0..511
            const int nb = idx >> 6;
            const int lane = idx & 63;
            const int n = nb * 16 + (lane & 15);
            const int k0 = k2 * 32 + (lane >> 4) * 8;
            u16x8 v;
#pragma unroll
            for (int j = 0; j < 8; ++j)
                v[j] = f2h_bits(W2[((size_t)r * 256 + k0 + j) * 128 + n]);
            *reinterpret_cast<u16x8*>(dst + idx * 8) = v;
        }
    }
}

// ---------------------------------------------------------------------------
// One evolution step (R19 structure: 4 waves / 256 thr, tile 64 rows,
// grid 512 = 2 blocks/CU, single Hs, LDS-only barriers, fragment-ordered
// coalesced weights with depth-2 rotation, launch_bounds(256,2)).
// NEW: the LAST step (step == n_evolve-1, runtime) fuses LayerNorm and
// writes directly to `out`, eliminating the separate ln_kernel and its
// 32 MB HBM round trip. Row mean/var via LDS-atomic block reduction in
// the (then-dead) Xs region.
// ---------------------------------------------------------------------------
__global__ __launch_bounds__(256, 2) void evolve_step(
    int step,
    const float* __restrict__ cells_in,
    float* __restrict__ buf0,
    float* __restrict__ buf1,
    const unsigned short* __restrict__ W1F,
    const unsigned short* __restrict__ W2F,
    const float* __restrict__ b1,
    const float* __restrict__ b2,
    const float* __restrict__ hdr,
    const float* __restrict__ ln_g,
    const float* __restrict__ ln_b,
    float* __restrict__ out)
{
    const int ne = (int)hdr[0];
    if (step >= ne) return;
    const float* src = (step == 0) ? cells_in : ((step & 1) ? buf0 : buf1);
    float* dst = (step & 1) ? buf1 : buf0;
    const float alpha = hdr[1];

    __shared__ __align__(16) unsigned short Xs[66 * 128];   // 16.9 KB
    __shared__ __align__(16) unsigned short Hs[64 * 256];   // 32 KB (single)

    const int tid = threadIdx.x;
    const int blk = blockIdx.x;
    const int b = blk >> 6;
    const int t0 = (blk & 63) << 6;
    const float* srcb = src + (size_t)b * (T_ * D_);

    // ---- stage X tile (float4 load -> pack4h -> b64 swizzled store) ----
    {
        const int cr = (tid & 31) << 2;
        for (int j = (tid >> 5); j < 66; j += 8) {
            const int tg = (t0 + j - 1) & (T_ - 1);
            const f32x4 v = *reinterpret_cast<const f32x4*>(srcb + tg * D_ + cr);
            int byte = (j * 128 + cr) * 2;
            byte ^= (j & 7) << 4;
            *reinterpret_cast<unsigned long long*>(reinterpret_cast<char*>(Xs) + byte) =
                pack4h(v[0], v[1], v[2], v[3]);
        }
    }
    __syncthreads();

    const int wave = tid >> 6;           // 0..3
    const int lane = tid & 63;
    const int l16 = lane & 15;
    const int lhi = lane >> 4;
    const int kbase = lhi * 8;
    const char* Xsb = reinterpret_cast<const char*>(Xs);
    char* Hsb = reinterpret_cast<char*>(Hs);

    const f32x4 z4 = {0.0f, 0.0f, 0.0f, 0.0f};
    f32x4 facc[2][4];   // [nf2][tf] -- wave owns 32 out cols
#pragma unroll
    for (int a = 0; a < 2; ++a)
#pragma unroll
        for (int bq = 0; bq < 4; ++bq) facc[a][bq] = z4;

    // fragment-ordered weight bases: per-lane offset is lane*8 u16 (16 B)
    const int lane8 = lane * 8;

#pragma unroll 1
    for (int r = 0; r < R_; ++r) {
        // W1F block (r, kk, nb=wave*4+nf): ((r*12+kk)*16 + wave*4+nf)*512
        const unsigned short* w1r = W1F + (size_t)r * (12 * 8192) + (size_t)(wave * 4) * 512 + lane8;
        // W2F block (r, k2, nb2=wave*2+nf2): ((r*8+k2)*8 + wave*2+nf2)*512
        const unsigned short* w2r = W2F + (size_t)r * (8 * 4096) + (size_t)(wave * 2) * 512 + lane8;

        // ======== rule-top issue: long-cover loads ========
        f16x8 wfr[3][4];     // GEMM1 weight slots (depth-2 rotation)
        f16x8 wfr2[3][2];    // GEMM2 weight slots (first two get GEMM1-length cover)
        f16x8 xfr[2][4];     // X fragments, dbuf
        f16x8 hfr[2][4];     // H fragments, dbuf
        f32x4 bv1[4], bv2[2];

#pragma unroll
        for (int nf = 0; nf < 4; ++nf) {
            wfr[0][nf] = __builtin_bit_cast(f16x8, *reinterpret_cast<const u16x8*>(w1r + nf * 512));
            wfr[1][nf] = __builtin_bit_cast(f16x8, *reinterpret_cast<const u16x8*>(w1r + 8192 + nf * 512));
            bv1[nf] = *reinterpret_cast<const f32x4*>(b1 + r * 256 + wave * 64 + nf * 16 + lhi * 4);
        }
#pragma unroll
        for (int nf2 = 0; nf2 < 2; ++nf2) {
            wfr2[0][nf2] = __builtin_bit_cast(f16x8, *reinterpret_cast<const u16x8*>(w2r + nf2 * 512));
            wfr2[1][nf2] = __builtin_bit_cast(f16x8, *reinterpret_cast<const u16x8*>(w2r + 4096 + nf2 * 512));
            bv2[nf2] = *reinterpret_cast<const f32x4*>(b2 + r * 128 + wave * 32 + nf2 * 16 + lhi * 4);
        }
#pragma unroll
        for (int tf = 0; tf < 4; ++tf) {
            const int row = tf * 16 + l16 + 1;   // kk=0: seg 0 -> rowadd 1
            int byte = row * 256 + kbase * 2;
            byte ^= (row & 7) << 4;
            xfr[0][tf] = __builtin_bit_cast(f16x8,
                *reinterpret_cast<const u16x8*>(Xsb + byte));
        }

        // ============ GEMM1: H^T = W1^T X^T ============
        f32x4 acc1[4][4];
#pragma unroll
        for (int a = 0; a < 4; ++a)
#pragma unroll
            for (int bq = 0; bq < 4; ++bq) acc1[a][bq] = z4;

#pragma unroll
        for (int kk = 0; kk < 12; ++kk) {
            if (kk < 10) {
                const size_t off = (size_t)(kk + 2) * 8192;
#pragma unroll
                for (int nf = 0; nf < 4; ++nf)
                    wfr[(kk + 2) % 3][nf] = __builtin_bit_cast(f16x8,
                        *reinterpret_cast<const u16x8*>(w1r + off + nf * 512));
            }
            if (kk < 11) {
                const int kn = kk + 1;
                const int segn = kn >> 2;
                const int rowaddn = (segn == 0) ? 1 : ((segn == 1) ? 0 : 2);
                const int klocn = ((kn & 3) * 32 + kbase) * 2;
#pragma unroll
                for (int tf = 0; tf < 4; ++tf) {
                    const int row = tf * 16 + l16 + rowaddn;
                    int byte = row * 256 + klocn;
                    byte ^= (row & 7) << 4;
                    xfr[(kk + 1) & 1][tf] = __builtin_bit_cast(f16x8,
                        *reinterpret_cast<const u16x8*>(Xsb + byte));
                }
            }
#pragma unroll
            for (int nf = 0; nf < 4; ++nf)
#pragma unroll
                for (int tf = 0; tf < 4; ++tf)
                    acc1[nf][tf] = __builtin_amdgcn_mfma_f32_16x16x32_f16(
                        wfr[kk % 3][nf], xfr[kk & 1][tf], acc1[nf][tf], 0, 0, 0);
        }

        LDS_BARRIER();   // previous rule's GEMM2 reads of Hs complete (WAR)

        // ---- bias + GELU -> Hs (b64 swizzled writes) ----
#pragma unroll
        for (int tf = 0; tf < 4; ++tf) {
            const int t = tf * 16 + l16;
            const int rowbyte = t * 512;
            const int swz = (t & 7) << 4;
#pragma unroll
            for (int nf = 0; nf < 4; ++nf) {
                const f32x4 a = acc1[nf][tf];
                const float g0 = gelu_fast(a[0] + bv1[nf][0]);
                const float g1 = gelu_fast(a[1] + bv1[nf][1]);
                const float g2 = gelu_fast(a[2] + bv1[nf][2]);
                const float g3 = gelu_fast(a[3] + bv1[nf][3]);
                int byte = rowbyte + wave * 128 + nf * 32 + lhi * 8;
                byte ^= swz;
                *reinterpret_cast<unsigned long long*>(Hsb + byte) =
                    pack4h(g0, g1, g2, g3);
            }
        }
        LDS_BARRIER();   // Hs visible to all waves (RAW)

        // ============ GEMM2: O^T = W2^T H^T ============
        f32x4 acc2[2][4];
#pragma unroll
        for (int a = 0; a < 2; ++a)
#pragma unroll
            for (int bq = 0; bq < 4; ++bq) acc2[a][bq] = z4;

#pragma unroll
        for (int tf = 0; tf < 4; ++tf) {
            const int t = tf * 16 + l16;
            int byte = t * 512 + kbase * 2;
            byte ^= (t & 7) << 4;
            hfr[0][tf] = __builtin_bit_cast(f16x8,
                *reinterpret_cast<const u16x8*>(Hsb + byte));
        }

#pragma unroll
        for (int k2 = 0; k2 < 8; ++k2) {
            if (k2 < 6) {
                const size_t off = (size_t)(k2 + 2) * 4096;
#pragma unroll
                for (int nf2 = 0; nf2 < 2; ++nf2)
                    wfr2[(k2 + 2) % 3][nf2] = __builtin_bit_cast(f16x8,
                        *reinterpret_cast<const u16x8*>(w2r + off + nf2 * 512));
            }
            if (k2 < 7) {
                const int kgn = ((k2 + 1) * 32 + kbase) * 2;
#pragma unroll
                for (int tf = 0; tf < 4; ++tf) {
                    const int t = tf * 16 + l16;
                    int byte = t * 512 + kgn;
                    byte ^= (t & 7) << 4;
                    hfr[(k2 + 1) & 1][tf] = __builtin_bit_cast(f16x8,
                        *reinterpret_cast<const u16x8*>(Hsb + byte));
                }
            }
#pragma unroll
            for (int nf2 = 0; nf2 < 2; ++nf2)
#pragma unroll
                for (int tf = 0; tf < 4; ++tf)
                    acc2[nf2][tf] = __builtin_amdgcn_mfma_f32_16x16x32_f16(
                        wfr2[k2 % 3][nf2], hfr[k2 & 1][tf], acc2[nf2][tf], 0, 0, 0);
        }

        const float rw = hdr[2 + r];
#pragma unroll
        for (int nf2 = 0; nf2 < 2; ++nf2)
#pragma unroll
            for (int tf = 0; tf < 4; ++tf)
#pragma unroll
                for (int i = 0; i < 4; ++i)
                    facc[nf2][tf][i] += rw * tanh_fast(acc2[nf2][tf][i] + bv2[nf2][i]);
    }

    // ---- epilogue: blend = alpha*x + (1-alpha)*new ----
    const float om = 1.0f - alpha;
#pragma unroll
    for (int tf = 0; tf < 4; ++tf) {
        const int t = t0 + tf * 16 + l16;
#pragma unroll
        for (int nf2 = 0; nf2 < 2; ++nf2) {
            const int c0 = wave * 32 + nf2 * 16 + lhi * 4;
            const size_t idx = (size_t)t * D_ + c0;
            const f32x4 x = *reinterpret_cast<const f32x4*>(srcb + idx);
#pragma unroll
            for (int i = 0; i < 4; ++i)
                facc[nf2][tf][i] = alpha * x[i] + om * facc[nf2][tf][i];
        }
    }

    if (step != ne - 1) {
        // normal step: raw state write to ping-pong buffer
        float* dstb = dst + (size_t)b * (T_ * D_);
#pragma unroll
        for (int tf = 0; tf < 4; ++tf) {
            const int t = t0 + tf * 16 + l16;
#pragma unroll
            for (int nf2 = 0; nf2 < 2; ++nf2) {
                const int c0 = wave * 32 + nf2 * 16 + lhi * 4;
                *reinterpret_cast<f32x4*>(dstb + (size_t)t * D_ + c0) = facc[nf2][tf];
            }
        }
        return;
    }

    // ---- LAST step: fused LayerNorm -> out ----
    // Block reduction of sum/sumsq per row via LDS atomics. Xs region is
    // dead here (all waves finished reading it before the last WAR barrier).
    float* red = reinterpret_cast<float*>(Xs);   // [64 rows][2]
    if (tid < 128) red[tid] = 0.0f;
    __syncthreads();
#pragma unroll
    for (int tf = 0; tf < 4; ++tf) {
        const int rl = tf * 16 + l16;      // local row 0..63
        float s = 0.0f, q = 0.0f;
#pragma unroll
        for (int nf2 = 0; nf2 < 2; ++nf2)
#pragma unroll
            for (int i = 0; i < 4; ++i) {
                const float v = facc[nf2][tf][i];
                s += v;
                q += v * v;
            }
        atomicAdd(&red[rl * 2], s);
        atomicAdd(&red[rl * 2 + 1], q);
    }
    __syncthreads();

    float* outb = out + (size_t)b * (T_ * D_);
#pragma unroll
    for (int tf = 0; tf < 4; ++tf) {
        const int rl = tf * 16 + l16;
        const int t = t0 + rl;
        const float mean = red[rl * 2] * (1.0f / 128.0f);
        float var = red[rl * 2 + 1] * (1.0f / 128.0f) - mean * mean;
        var = fmaxf(var, 0.0f);
        const float rstd = rsqrtf(var + 1e-5f);
#pragma unroll
        for (int nf2 = 0; nf2 < 2; ++nf2) {
            const int c0 = wave * 32 + nf2 * 16 + lhi * 4;
            const f32x4 g = *reinterpret_cast<const f32x4*>(ln_g + c0);
            const f32x4 bb = *reinterpret_cast<const f32x4*>(ln_b + c0);
            f32x4 o;
#pragma unroll
            for (int i = 0; i < 4; ++i)
                o[i] = (facc[nf2][tf][i] - mean) * rstd * g[i] + bb[i];
            *reinterpret_cast<f32x4*>(outb + (size_t)t * D_ + c0) = o;
        }
    }
}

// ---------------------------------------------------------------------------
extern "C" void kernel_launch(void* const* d_in, const int* in_sizes, int n_in,
                              void* d_out, int out_size, void* d_ws, size_t ws_size,
                              hipStream_t stream)
{
    (void)in_sizes; (void)n_in; (void)out_size; (void)ws_size;
    const float* cells  = (const float*)d_in[0];
    const float* cst    = (const float*)d_in[1];
    const float* W1     = (const float*)d_in[2];
    const float* b1     = (const float*)d_in[3];
    const float* W2     = (const float*)d_in[4];
    const float* b2     = (const float*)d_in[5];
    const float* rW1    = (const float*)d_in[6];
    const float* rb1    = (const float*)d_in[7];
    const float* rW2    = (const float*)d_in[8];
    const float* rb2    = (const float*)d_in[9];
    const float* sW1    = (const float*)d_in[10];
    const float* sb1    = (const float*)d_in[11];
    const float* sW2    = (const float*)d_in[12];
    const float* sb2    = (const float*)d_in[13];
    const float* aW1    = (const float*)d_in[14];
    const float* ab1    = (const float*)d_in[15];
    const float* aW2    = (const float*)d_in[16];
    const float* ab2    = (const float*)d_in[17];
    const float* ln_g   = (const float*)d_in[18];
    const float* ln_b   = (const float*)d_in[19];
    float* out = (float*)d_out;

    char* ws = (char*)d_ws;
    float* hdr  = (float*)ws;                                      // 256 B
    float* buf0 = (float*)(ws + 256);                              // 16 MiB
    float* buf1 = (float*)(ws + 256 + 16777216);                   // 16 MiB
    unsigned short* W1F = (unsigned short*)(ws + 256 + 2 * 16777216);  // 1.5 MiB
    unsigned short* W2F = W1F + (size_t)96 * 8192;                     // 0.5 MiB

    hipLaunchKernelGGL(prep_weights, dim3(160), dim3(256), 0, stream, W1, W2, W1F, W2F);
    hipLaunchKernelGGL(selectors_kernel, dim3(1), dim3(64), 0, stream,
                       cst, rW1, rb1, rW2, rb2, sW1, sb1, sW2, sb2,
                       aW1, ab1, aW2, ab2, hdr);
    for (int s = 0; s < 8; ++s) {
        hipLaunchKernelGGL(evolve_step, dim3(512), dim3(256), 0, stream,
                           s, cells, buf0, buf1, W1F, W2F, b1, b2, hdr,
                           ln_g, ln_b, out);
    }
}

// Round 23
// 559.486 us; speedup vs baseline: 1.1694x; 1.0330x over previous
//
#include <hip/hip_runtime.h>
#include <math.h>

#define T_ 4096
#define D_ 128
#define R_ 8

// LDS-only barrier: drains lgkmcnt, leaves global prefetches (vmcnt) in flight.
#define LDS_BARRIER() asm volatile("s_waitcnt lgkmcnt(0)\n\ts_barrier" ::: "memory")

typedef float f32x4 __attribute__((ext_vector_type(4)));
typedef _Float16 f16x8 __attribute__((ext_vector_type(8)));
typedef unsigned short u16x8 __attribute__((ext_vector_type(8)));

__device__ __forceinline__ unsigned short f2h_bits(float f) {
    _Float16 h = (_Float16)f;
    return __builtin_bit_cast(unsigned short, h);
}

__device__ __forceinline__ unsigned long long pack4h(float a, float b, float c, float d) {
    unsigned int lo = __builtin_bit_cast(unsigned int, __builtin_amdgcn_cvt_pkrtz(a, b));
    unsigned int hi = __builtin_bit_cast(unsigned int, __builtin_amdgcn_cvt_pkrtz(c, d));
    return ((unsigned long long)hi << 32) | (unsigned long long)lo;
}

// tanh(x) = 1 - 2/(exp2(2*log2e*x)+1); large-|x| safe
__device__ __forceinline__ float tanh_fast(float x) {
    float e = __builtin_amdgcn_exp2f(x * 2.885390082f);
    float r = __builtin_amdgcn_rcpf(e + 1.0f);
    return fmaf(-2.0f, r, 1.0f);
}

// tanh-approx GELU: |err| ~1e-3 vs erf form (budget is 2%)
__device__ __forceinline__ float gelu_fast(float x) {
    float x2 = x * x;
    float u = x * fmaf(x2, 0.044715f, 1.0f);
    float e = __builtin_amdgcn_exp2f(u * -2.3022082f);
    return x * __builtin_amdgcn_rcpf(1.0f + e);
}

__device__ __forceinline__ float gelu_exact(float x) {
    return 0.5f * x * (1.0f + erff(x * 0.7071067811865475f));
}

// ---------------------------------------------------------------------------
// Selector MLPs (tiny): hdr[0]=n_evolve, hdr[1]=alpha, hdr[2..9]=rule_weights
// ---------------------------------------------------------------------------
__global__ void selectors_kernel(
    const float* __restrict__ c,
    const float* __restrict__ rW1, const float* __restrict__ rb1,
    const float* __restrict__ rW2, const float* __restrict__ rb2,
    const float* __restrict__ sW1, const float* __restrict__ sb1,
    const float* __restrict__ sW2, const float* __restrict__ sb2,
    const float* __restrict__ aW1, const float* __restrict__ ab1,
    const float* __restrict__ aW2, const float* __restrict__ ab2,
    float* __restrict__ hdr)
{
    __shared__ float cs[128];
    __shared__ float hb[64];
    __shared__ float lg[8];
    const int l = threadIdx.x;  // 64 threads
    cs[l] = c[l];
    cs[l + 64] = c[l + 64];
    __syncthreads();

    // rule selector: 128 -> 64 -> 8 -> softmax
    {
        float acc = rb1[l];
        for (int k = 0; k < 128; ++k) acc += cs[k] * rW1[k * 64 + l];
        hb[l] = gelu_exact(acc);
    }
    __syncthreads();
    if (l < 8) {
        float acc = rb2[l];
        for (int j = 0; j < 64; ++j) acc += hb[j] * rW2[j * 8 + l];
        lg[l] = acc;
    }
    __syncthreads();
    if (l == 0) {
        float mx = lg[0];
        for (int o = 1; o < 8; ++o) mx = fmaxf(mx, lg[o]);
        float e[8], se = 0.0f;
        for (int o = 0; o < 8; ++o) { e[o] = expf(lg[o] - mx); se += e[o]; }
        for (int o = 0; o < 8; ++o) hdr[2 + o] = e[o] / se;
    }
    __syncthreads();

    // steps selector: 128 -> 32 -> 7 -> softmax -> n_evolve
    if (l < 32) {
        float acc = sb1[l];
        for (int k = 0; k < 128; ++k) acc += cs[k] * sW1[k * 32 + l];
        hb[l] = gelu_exact(acc);
    }
    __syncthreads();
    if (l < 7) {
        float acc = sb2[l];
        for (int j = 0; j < 32; ++j) acc += hb[j] * sW2[j * 7 + l];
        lg[l] = acc;
    }
    __syncthreads();
    if (l == 0) {
        float mx = lg[0];
        for (int o = 1; o < 7; ++o) mx = fmaxf(mx, lg[o]);
        float e[7], se = 0.0f;
        for (int o = 0; o < 7; ++o) { e[o] = expf(lg[o] - mx); se += e[o]; }
        float n_soft = 0.0f;
        for (int o = 0; o < 7; ++o) n_soft += (e[o] / se) * (float)(2 + o);
        int ne = (int)floorf(n_soft + 0.5f);
        ne = ne < 2 ? 2 : (ne > 8 ? 8 : ne);
        hdr[0] = (float)ne;
    }
    __syncthreads();

    // alpha selector: 128 -> 32 -> 1 -> sigmoid
    if (l < 32) {
        float acc = ab1[l];
        for (int k = 0; k < 128; ++k) acc += cs[k] * aW1[k * 32 + l];
        hb[l] = gelu_exact(acc);
    }
    __syncthreads();
    if (l == 0) {
        float acc = ab2[0];
        for (int j = 0; j < 32; ++j) acc += hb[j] * aW2[j];
        hdr[1] = 0.1f + 0.8f / (1.0f + expf(-acc));
    }
}

// ---------------------------------------------------------------------------
// Weight prep -> FRAGMENT-ORDERED layout.
// W1F block (r,kk,nb): 64 lanes x 16B, lane = lhi*16+l16 holds
//   n = nb*16+l16, k = kk*32+lhi*8 .. +8. A wave's fragment load is ONE
//   contiguous 1KB access (4 cache lines) instead of 16 scattered lines.
// W2F likewise: block (r,k2,nb=wave).
// ---------------------------------------------------------------------------
__global__ __launch_bounds__(256) void prep_weights(
    const float* __restrict__ W1, const float* __restrict__ W2,
    unsigned short* __restrict__ W1F, unsigned short* __restrict__ W2F)
{
    const int bx = blockIdx.x;
    const int t = threadIdx.x;
    if (bx < 96) {                      // W1: (r, kk) pairs, 8*12
        const int r = bx / 12;
        const int kk = bx % 12;
        unsigned short* dst = W1F + (size_t)bx * 8192;   // 16 nb * 64 lanes * 8
#pragma unroll
        for (int i = 0; i < 4; ++i) {
            const int idx = i * 256 + t;                  // 0..1023
            const int nb = idx >> 6;
            const int lane = idx & 63;
            const int n = nb * 16 + (lane & 15);
            const int k0 = kk * 32 + (lane >> 4) * 8;
            u16x8 v;
#pragma unroll
            for (int j = 0; j < 8; ++j)
                v[j] = f2h_bits(W1[((size_t)r * 384 + k0 + j) * 256 + n]);
            *reinterpret_cast<u16x8*>(dst + idx * 8) = v;
        }
    } else {                            // W2: (r, k2) pairs, 8*8
        const int b2 = bx - 96;
        const int r = b2 >> 3;
        const int k2 = b2 & 7;
        unsigned short* dst = W2F + (size_t)b2 * 4096;   // 8 nb * 64 * 8
#pragma unroll
        for (int i = 0; i < 2; ++i) {
            const int idx = i * 256 + t;                  // 0..511
            const int nb = idx >> 6;
            const int lane = idx & 63;
            const int n = nb * 16 + (lane & 15);
            const int k0 = k2 * 32 + (lane >> 4) * 8;
            u16x8 v;
#pragma unroll
            for (int j = 0; j < 8; ++j)
                v[j] = f2h_bits(W2[((size_t)r * 256 + k0 + j) * 128 + n]);
            *reinterpret_cast<u16x8*>(dst + idx * 8) = v;
        }
    }
}

// ---------------------------------------------------------------------------
// One evolution step. R15 structure verbatim (rule-pipelined, Hs dbuf,
// depth-2 weight rotation, LDS-only barriers, XOR-swizzled LDS) with ONE
// change: weight loads read the fragment-ordered W1F/W2F layout --
// each load is base + lane*16B, fully coalesced (4 lines vs 16).
// ---------------------------------------------------------------------------
__global__ __launch_bounds__(512, 2) void evolve_step(
    int step,
    const float* __restrict__ cells_in,
    float* __restrict__ buf0,
    float* __restrict__ buf1,
    const unsigned short* __restrict__ W1F,
    const unsigned short* __restrict__ W2F,
    const float* __restrict__ b1,
    const float* __restrict__ b2,
    const float* __restrict__ hdr)
{
    if (step >= (int)hdr[0]) return;
    const float* src = (step == 0) ? cells_in : ((step & 1) ? buf0 : buf1);
    float* dst = (step & 1) ? buf1 : buf0;
    const float alpha = hdr[1];

    __shared__ __align__(16) unsigned short Xs[66 * 128];      // 16.9 KB
    __shared__ __align__(16) unsigned short Hs[2 * 64 * 256];  // 64 KB dbuf

    const int tid = threadIdx.x;
    const int blk = blockIdx.x;
    const int b = blk >> 6;
    const int t0 = (blk & 63) << 6;
    const float* srcb = src + (size_t)b * (T_ * D_);

    // ---- stage X tile (float4 load -> pack4h -> b64 swizzled store) ----
    {
        const int cr = (tid & 31) << 2;
        for (int j = (tid >> 5); j < 66; j += 16) {
            const int tg = (t0 + j - 1) & (T_ - 1);
            const f32x4 v = *reinterpret_cast<const f32x4*>(srcb + tg * D_ + cr);
            int byte = (j * 128 + cr) * 2;
            byte ^= (j & 7) << 4;
            *reinterpret_cast<unsigned long long*>(reinterpret_cast<char*>(Xs) + byte) =
                pack4h(v[0], v[1], v[2], v[3]);
        }
    }
    __syncthreads();

    const int wave = tid >> 6;           // 0..7
    const int lane = tid & 63;
    const int l16 = lane & 15;
    const int lhi = lane >> 4;
    const int kbase = lhi * 8;
    const char* Xsb = reinterpret_cast<const char*>(Xs);
    char* Hsb = reinterpret_cast<char*>(Hs);

    const f32x4 z4 = {0.0f, 0.0f, 0.0f, 0.0f};
    f32x4 facc[4];   // [tf] -- wave owns 16 out cols
#pragma unroll
    for (int bq = 0; bq < 4; ++bq) facc[bq] = z4;

    // fragment-ordered weight bases: per-lane offset is lane*8 u16 (16 B)
    const int lane8 = lane * 8;

#pragma unroll 1
    for (int r = 0; r <= R_; ++r) {
        // W1F block index for (r, kk, nb = wave*2+nf): ((r*12+kk)*16 + wave*2+nf)*512
        const unsigned short* w1r = W1F + (size_t)r * (12 * 8192) + (size_t)(wave * 2) * 512 + lane8;
        // W2F block index for (r-1, k2, nb = wave): (((r-1)*8+k2)*8 + wave)*512
        const unsigned short* w2r = W2F + (size_t)(r - 1) * (8 * 4096) + (size_t)wave * 512 + lane8;

        // ======== interval-top issue: long-cover loads ========
        f16x8 wfr[3][2];     // GEMM1 weight slots (depth-2 rotation)
        f16x8 wfr2[3];       // GEMM2 weight slots
        f16x8 xfr[2][4];     // X fragments, dbuf
        f16x8 hfr[2][4];     // H fragments, dbuf
        f32x4 bv1[2], bv2;

        if (r < R_) {
            wfr[0][0] = __builtin_bit_cast(f16x8, *reinterpret_cast<const u16x8*>(w1r));
            wfr[0][1] = __builtin_bit_cast(f16x8, *reinterpret_cast<const u16x8*>(w1r + 512));
            wfr[1][0] = __builtin_bit_cast(f16x8, *reinterpret_cast<const u16x8*>(w1r + 8192));
            wfr[1][1] = __builtin_bit_cast(f16x8, *reinterpret_cast<const u16x8*>(w1r + 8192 + 512));
            bv1[0] = *reinterpret_cast<const f32x4*>(b1 + r * 256 + wave * 32 + lhi * 4);
            bv1[1] = *reinterpret_cast<const f32x4*>(b1 + r * 256 + wave * 32 + 16 + lhi * 4);
#pragma unroll
            for (int tf = 0; tf < 4; ++tf) {
                const int row = tf * 16 + l16 + 1;   // kk=0: seg 0 -> rowadd 1
                int byte = row * 256 + kbase * 2;
                byte ^= (row & 7) << 4;
                xfr[0][tf] = __builtin_bit_cast(f16x8,
                    *reinterpret_cast<const u16x8*>(Xsb + byte));
            }
        }
        if (r > 0) {
            wfr2[0] = __builtin_bit_cast(f16x8, *reinterpret_cast<const u16x8*>(w2r));
            wfr2[1] = __builtin_bit_cast(f16x8, *reinterpret_cast<const u16x8*>(w2r + 4096));
            bv2 = *reinterpret_cast<const f32x4*>(b2 + (r - 1) * 128 + wave * 16 + lhi * 4);
            const char* hrd = Hsb + ((r - 1) & 1) * 32768;
#pragma unroll
            for (int tf = 0; tf < 4; ++tf) {
                const int t = tf * 16 + l16;
                int byte = t * 512 + kbase * 2;
                byte ^= (t & 7) << 4;
                hfr[0][tf] = __builtin_bit_cast(f16x8,
                    *reinterpret_cast<const u16x8*>(hrd + byte));
            }
        }

        // ============ stage A: GEMM1(r) -> GELU -> Hs[r&1] ============
        if (r < R_) {
            f32x4 acc1[2][4];
#pragma unroll
            for (int a = 0; a < 2; ++a)
#pragma unroll
                for (int bq = 0; bq < 4; ++bq) acc1[a][bq] = z4;

#pragma unroll
            for (int kk = 0; kk < 12; ++kk) {
                // depth-2 weight prefetch: load kk+2 into slot (kk+2)%3
                if (kk < 10) {
                    const size_t off = (size_t)(kk + 2) * 8192;
                    wfr[(kk + 2) % 3][0] = __builtin_bit_cast(f16x8,
                        *reinterpret_cast<const u16x8*>(w1r + off));
                    wfr[(kk + 2) % 3][1] = __builtin_bit_cast(f16x8,
                        *reinterpret_cast<const u16x8*>(w1r + off + 512));
                }
                // depth-1 X prefetch (LDS)
                if (kk < 11) {
                    const int kn = kk + 1;
                    const int segn = kn >> 2;
                    const int rowaddn = (segn == 0) ? 1 : ((segn == 1) ? 0 : 2);
                    const int klocn = ((kn & 3) * 32 + kbase) * 2;
#pragma unroll
                    for (int tf = 0; tf < 4; ++tf) {
                        const int row = tf * 16 + l16 + rowaddn;
                        int byte = row * 256 + klocn;
                        byte ^= (row & 7) << 4;
                        xfr[(kk + 1) & 1][tf] = __builtin_bit_cast(f16x8,
                            *reinterpret_cast<const u16x8*>(Xsb + byte));
                    }
                }
#pragma unroll
                for (int nf = 0; nf < 2; ++nf)
#pragma unroll
                    for (int tf = 0; tf < 4; ++tf)
                        acc1[nf][tf] = __builtin_amdgcn_mfma_f32_16x16x32_f16(
                            wfr[kk % 3][nf], xfr[kk & 1][tf], acc1[nf][tf], 0, 0, 0);
            }

            // bias + GELU -> Hs[r&1]
            char* hw = Hsb + (r & 1) * 32768;
#pragma unroll
            for (int tf = 0; tf < 4; ++tf) {
                const int t = tf * 16 + l16;
                const int rowbyte = t * 512;
                const int swz = (t & 7) << 4;
#pragma unroll
                for (int nf = 0; nf < 2; ++nf) {
                    const f32x4 a = acc1[nf][tf];
                    const float g0 = gelu_fast(a[0] + bv1[nf][0]);
                    const float g1 = gelu_fast(a[1] + bv1[nf][1]);
                    const float g2 = gelu_fast(a[2] + bv1[nf][2]);
                    const float g3 = gelu_fast(a[3] + bv1[nf][3]);
                    int byte = rowbyte + wave * 64 + nf * 32 + lhi * 8;
                    byte ^= swz;
                    *reinterpret_cast<unsigned long long*>(hw + byte) =
                        pack4h(g0, g1, g2, g3);
                }
            }
        }

        // ============ stage B: GEMM2(r-1) from Hs[(r-1)&1] ============
        if (r > 0) {
            f32x4 acc2[4];
#pragma unroll
            for (int bq = 0; bq < 4; ++bq) acc2[bq] = z4;

            const char* hrd = Hsb + ((r - 1) & 1) * 32768;

#pragma unroll
            for (int k2 = 0; k2 < 8; ++k2) {
                if (k2 < 6) {
                    wfr2[(k2 + 2) % 3] = __builtin_bit_cast(f16x8,
                        *reinterpret_cast<const u16x8*>(w2r + (size_t)(k2 + 2) * 4096));
                }
                if (k2 < 7) {
                    const int kgn = ((k2 + 1) * 32 + kbase) * 2;
#pragma unroll
                    for (int tf = 0; tf < 4; ++tf) {
                        const int t = tf * 16 + l16;
                        int byte = t * 512 + kgn;
                        byte ^= (t & 7) << 4;
                        hfr[(k2 + 1) & 1][tf] = __builtin_bit_cast(f16x8,
                            *reinterpret_cast<const u16x8*>(hrd + byte));
                    }
                }
#pragma unroll
                for (int tf = 0; tf < 4; ++tf)
                    acc2[tf] = __builtin_amdgcn_mfma_f32_16x16x32_f16(
                        wfr2[k2 % 3], hfr[k2 & 1][tf], acc2[tf], 0, 0, 0);
            }

            const float rw = hdr[2 + (r - 1)];
#pragma unroll
            for (int tf = 0; tf < 4; ++tf)
#pragma unroll
                for (int i = 0; i < 4; ++i)
                    facc[tf][i] += rw * tanh_fast(acc2[tf][i] + bv2[i]);
        }

        LDS_BARRIER();   // one LDS-only barrier per rule iteration
    }

    // ---- epilogue: cells = alpha*x + (1-alpha)*new, f32x4 in/out ----
    float* dstb = dst + (size_t)b * (T_ * D_);
    const float om = 1.0f - alpha;
    const int c0 = wave * 16 + lhi * 4;
#pragma unroll
    for (int tf = 0; tf < 4; ++tf) {
        const int t = t0 + tf * 16 + l16;
        const size_t idx = (size_t)t * D_ + c0;
        const f32x4 x = *reinterpret_cast<const f32x4*>(srcb + idx);
        f32x4 o;
#pragma unroll
        for (int i = 0; i < 4; ++i) o[i] = alpha * x[i] + om * facc[tf][i];
        *reinterpret_cast<f32x4*>(dstb + idx) = o;
    }
}

// ---------------------------------------------------------------------------
// LayerNorm over D=128. One wave per row, 2 elems/lane.
// ---------------------------------------------------------------------------
__global__ __launch_bounds__(256) void ln_kernel(
    const float* __restrict__ buf0, const float* __restrict__ buf1,
    const float* __restrict__ hdr,
    const float* __restrict__ g, const float* __restrict__ bb,
    float* __restrict__ out)
{
    const int ne = (int)hdr[0];
    const float* src = ((ne - 1) & 1) ? buf1 : buf0;   // step s writes buf[s&1]
    const int row = blockIdx.x * 4 + (threadIdx.x >> 6);
    const int lane = threadIdx.x & 63;
    const size_t base = (size_t)row * D_;
    const int d = lane * 2;
    const float a = src[base + d];
    const float c = src[base + d + 1];
    float s = a + c;
    float q = a * a + c * c;
#pragma unroll
    for (int off = 32; off >= 1; off >>= 1) {
        s += __shfl_xor(s, off);
        q += __shfl_xor(q, off);
    }
    const float mean = s * (1.0f / 128.0f);
    float var = q * (1.0f / 128.0f) - mean * mean;
    var = fmaxf(var, 0.0f);
    const float rstd = rsqrtf(var + 1e-5f);
    out[base + d]     = (a - mean) * rstd * g[d] + bb[d];
    out[base + d + 1] = (c - mean) * rstd * g[d + 1] + bb[d + 1];
}

// ---------------------------------------------------------------------------
extern "C" void kernel_launch(void* const* d_in, const int* in_sizes, int n_in,
                              void* d_out, int out_size, void* d_ws, size_t ws_size,
                              hipStream_t stream)
{
    (void)in_sizes; (void)n_in; (void)out_size; (void)ws_size;
    const float* cells  = (const float*)d_in[0];
    const float* cst    = (const float*)d_in[1];
    const float* W1     = (const float*)d_in[2];
    const float* b1     = (const float*)d_in[3];
    const float* W2     = (const float*)d_in[4];
    const float* b2     = (const float*)d_in[5];
    const float* rW1    = (const float*)d_in[6];
    const float* rb1    = (const float*)d_in[7];
    const float* rW2    = (const float*)d_in[8];
    const float* rb2    = (const float*)d_in[9];
    const float* sW1    = (const float*)d_in[10];
    const float* sb1    = (const float*)d_in[11];
    const float* sW2    = (const float*)d_in[12];
    const float* sb2    = (const float*)d_in[13];
    const float* aW1    = (const float*)d_in[14];
    const float* ab1    = (const float*)d_in[15];
    const float* aW2    = (const float*)d_in[16];
    const float* ab2    = (const float*)d_in[17];
    const float* ln_g   = (const float*)d_in[18];
    const float* ln_b   = (const float*)d_in[19];
    float* out = (float*)d_out;

    char* ws = (char*)d_ws;
    float* hdr  = (float*)ws;                                      // 256 B
    float* buf0 = (float*)(ws + 256);                              // 16 MiB
    unsigned short* W1F = (unsigned short*)(ws + 256 + 16777216);  // 1.5 MiB
    unsigned short* W2F = W1F + (size_t)96 * 8192;                 // 0.5 MiB
    float* buf1 = out;  // d_out doubles as ping-pong buffer (LN is in-place safe)

    hipLaunchKernelGGL(prep_weights, dim3(160), dim3(256), 0, stream, W1, W2, W1F, W2F);
    hipLaunchKernelGGL(selectors_kernel, dim3(1), dim3(64), 0, stream,
                       cst, rW1, rb1, rW2, rb2, sW1, sb1, sW2, sb2,
                       aW1, ab1, aW2, ab2, hdr);
    for (int s = 0; s < 8; ++s) {
        hipLaunchKernelGGL(evolve_step, dim3(512), dim3(512), 0, stream,
                           s, cells, buf0, buf1, W1F, W2F, b1, b2, hdr);
    }
    hipLaunchKernelGGL(ln_kernel, dim3(8192), dim3(256), 0, stream,
                       buf0, buf1, hdr, ln_g, ln_b, out);
}